// Round 21
// baseline (116.437 us; speedup 1.0000x reference)
//
#include <hip/hip_runtime.h>
#include <math.h>

namespace {
constexpr int B = 4, R = 10, N = 64, E = 64, D = 300, H = 512;
constexpr int BR = B * R;        // 40
constexpr int NE = N * E;        // 4096
constexpr int S = BR * NE;       // 163840
constexpr float SLOPE = 0.2f;
constexpr int WO_BLOCKS = BR * 8;        // 320
constexpr int S2_ROWS = 32;              // rows per block (38.4 KB contiguous slab)
constexpr int S2_BLOCKS = S / S2_ROWS;   // 5120

// ws layout (floats) — identical to R20
constexpr int OFF_V1  = 0;                 // 300   Wn @ a1
constexpr int OFF_V2  = OFF_V1 + 300;      // 300   Wn @ a2
constexpr int OFF_U1  = OFF_V2 + 300;      // 512   Wq @ a1
constexpr int OFF_U2  = OFF_U1 + H;        // 512   Wq @ a2
constexpr int OFF_QP  = OFF_U2 + H;        // 40*512 q_proj
constexpr int OFF_QA1 = OFF_QP + BR * H;   // 40
constexpr int OFF_QA2 = OFF_QA1 + BR;      // 40
constexpr int OFF_S1  = OFF_QA2 + BR;      // 2560  scores1[b,r,n] (incl. qa1)
constexpr int OFF_RAW = OFF_S1 + BR * N;   // 163840 raw adj.v2 dots (pre-leaky)
constexpr int OFF_SC  = OFF_RAW + S;       // 163840 (unused this round)
constexpr int OFF_WO  = OFF_SC + S;        // 1310720 w_original
}

__device__ inline float waveReduce(float v) {
#pragma unroll
  for (int o = 32; o > 0; o >>= 1) v += __shfl_xor(v, o, 64);
  return v;
}

__device__ inline float dot4(float4 a, float4 b) {
  return a.x * b.x + a.y * b.y + a.z * b.z + a.w * b.w;
}

// grid 812 x 64: one wave per W row; dot with a1 and a2.
__global__ __launch_bounds__(64) void k_vecs(const float* __restrict__ W,
                                             const float* __restrict__ a,
                                             float* __restrict__ ws) {
  int row = blockIdx.x;
  int lane = threadIdx.x;
  const float4* rf  = reinterpret_cast<const float4*>(W + (size_t)row * H);
  const float4* a1f = reinterpret_cast<const float4*>(a);
  const float4* a2f = reinterpret_cast<const float4*>(a + H);
  float4 x0 = rf[lane], x1 = rf[64 + lane];
  float4 p0 = a1f[lane], p1 = a1f[64 + lane];
  float4 q0 = a2f[lane], q1 = a2f[64 + lane];
  float s1 = dot4(x0, p0) + dot4(x1, p1);
  float s2 = dot4(x0, q0) + dot4(x1, q1);
  s1 = waveReduce(s1);
  s2 = waveReduce(s2);
  if (lane == 0) {
    if (row < D) { ws[OFF_V1 + row] = s1; ws[OFF_V2 + row] = s2; }
    else         { ws[OFF_U1 + (row - D)] = s1; ws[OFF_U2 + (row - D)] = s2; }
  }
}

// grid 40 x 512: q_proj (4-way ILP accumulators) + qa1/qa2 + scores1 (2-row batch).
__global__ __launch_bounds__(512) void k_qproj_s1(const float* __restrict__ ques,
                                                  const float* __restrict__ W,
                                                  const float* __restrict__ orig,
                                                  float* __restrict__ ws) {
  int br = blockIdx.x, h = threadIdx.x;
  __shared__ float qs[H];
  __shared__ float red[16];
  __shared__ float qa1s;
  qs[h] = ques[(size_t)br * H + h];
  __syncthreads();
  float ac0 = 0.f, ac1 = 0.f, ac2 = 0.f, ac3 = 0.f;
#pragma unroll 4
  for (int q = 0; q < H; q += 4) {
    ac0 = fmaf(qs[q + 0], W[(size_t)(D + q + 0) * H + h], ac0);
    ac1 = fmaf(qs[q + 1], W[(size_t)(D + q + 1) * H + h], ac1);
    ac2 = fmaf(qs[q + 2], W[(size_t)(D + q + 2) * H + h], ac2);
    ac3 = fmaf(qs[q + 3], W[(size_t)(D + q + 3) * H + h], ac3);
  }
  float acc = (ac0 + ac1) + (ac2 + ac3);
  ws[OFF_QP + br * H + h] = acc;
  float p1 = qs[h] * ws[OFF_U1 + h];
  float p2 = qs[h] * ws[OFF_U2 + h];
  p1 = waveReduce(p1);
  p2 = waveReduce(p2);
  int lane = h & 63, wave = h >> 6;
  if (lane == 0) { red[wave] = p1; red[8 + wave] = p2; }
  __syncthreads();
  if (h == 0) {
    float t1 = 0.f, t2 = 0.f;
#pragma unroll
    for (int i = 0; i < 8; ++i) { t1 += red[i]; t2 += red[8 + i]; }
    ws[OFF_QA1 + br] = t1;
    ws[OFF_QA2 + br] = t2;
    qa1s = t1;
  }
  __syncthreads();
  float qa1 = qa1s;
  const float4* vf = reinterpret_cast<const float4*>(ws + OFF_V1);
  float4 va = vf[lane];
  float4 vb = (lane < 11) ? vf[64 + lane] : make_float4(0.f, 0.f, 0.f, 0.f);
  for (int n2 = wave * 8; n2 < wave * 8 + 8; n2 += 2) {
    const float4* rf0 = reinterpret_cast<const float4*>(orig + ((size_t)br * N + n2) * D);
    const float4* rf1 = reinterpret_cast<const float4*>(orig + ((size_t)br * N + n2 + 1) * D);
    float a0 = dot4(rf0[lane], va);
    float a1 = dot4(rf1[lane], va);
    if (lane < 11) {
      a0 += dot4(rf0[64 + lane], vb);
      a1 += dot4(rf1[64 + lane], vb);
    }
#pragma unroll
    for (int o = 32; o > 0; o >>= 1) {
      a0 += __shfl_xor(a0, o, 64);
      a1 += __shfl_xor(a1, o, 64);
    }
    if (lane == 0) {
      ws[OFF_S1 + br * N + n2]     = a0 + qa1;
      ws[OFF_S1 + br * N + n2 + 1] = a1 + qa1;
    }
  }
}

// grid 5440 x 256, block-split (minimal-boundary consolidation):
//   blocks 0..319:    wo GEMM (br, h0) — R16-measured structure (acc[4][4],
//                     BK=60); runs first, VALU work overlaps s2's HBM waits.
//   blocks 320..5439: s2 streaming — R20-measured structure: each block's 32
//                     rows are a CONTIGUOUS, 64B-ALIGNED 38.4KB slab of adj ->
//                     perfectly-coalesced float4 global->LDS copy, then 8
//                     threads/row dot from LDS (75->77 float4 pad, conflict-
//                     free), 3-step shfl reduce, write RAW.
__global__ __launch_bounds__(256) void k_s2wo(const float* __restrict__ adj,
                                              const float* __restrict__ orig,
                                              const float* __restrict__ W,
                                              float* __restrict__ ws) {
  __shared__ __align__(16) float smem[S2_ROWS * 77 * 4];   // 39424 B union
  int t = threadIdx.x;
  if (blockIdx.x < WO_BLOCKS) {
    // ---- w_original tile GEMM (R16 branch, verbatim) ----
    int bi = blockIdx.x;
    int br = bi >> 3, h0 = (bi & 7) * 64;
    float* sA = smem;             // 64 x 60
    float* sB = smem + 3840;      // 60 x 64
    const float4* sBf = reinterpret_cast<const float4*>(sB);
    int tn = t >> 4, th = t & 15;
    float acc[4][4] = {};
    for (int k0 = 0; k0 < D; k0 += 60) {
      __syncthreads();
      for (int idx = t; idx < 64 * 60; idx += 256) {
        int n = idx / 60, kk = idx % 60;
        sA[idx] = orig[((size_t)br * N + n) * D + k0 + kk];
      }
      for (int idx = t; idx < 60 * 64; idx += 256) {
        int kk = idx >> 6, hh = idx & 63;
        sB[idx] = W[(size_t)(k0 + kk) * H + h0 + hh];
      }
      __syncthreads();
#pragma unroll 4
      for (int kk = 0; kk < 60; ++kk) {
        float av[4];
#pragma unroll
        for (int i = 0; i < 4; ++i) av[i] = sA[(tn * 4 + i) * 60 + kk];
        float4 bv = sBf[kk * 16 + th];
#pragma unroll
        for (int i = 0; i < 4; ++i) {
          acc[i][0] = fmaf(av[i], bv.x, acc[i][0]);
          acc[i][1] = fmaf(av[i], bv.y, acc[i][1]);
          acc[i][2] = fmaf(av[i], bv.z, acc[i][2]);
          acc[i][3] = fmaf(av[i], bv.w, acc[i][3]);
        }
      }
    }
#pragma unroll
    for (int i = 0; i < 4; ++i) {
      int n = tn * 4 + i;
#pragma unroll
      for (int j = 0; j < 4; ++j) {
        int h = h0 + th * 4 + j;
        ws[OFF_WO + ((size_t)br * N + n) * H + h] = acc[i][j] + ws[OFF_QP + br * H + h];
      }
    }
    return;
  }
  // ---- s2 streaming slab (R20 branch, verbatim) ----
  float4* slab = reinterpret_cast<float4*>(smem);
  int sb = blockIdx.x - WO_BLOCKS;
  const float4* src = reinterpret_cast<const float4*>(adj) + (size_t)sb * (S2_ROWS * 75);
  for (int i = t; i < S2_ROWS * 75; i += 256) {
    slab[(i / 75) * 77 + (i % 75)] = src[i];
  }
  __syncthreads();
  int row = t >> 3, g = t & 7;
  const float4* v4 = reinterpret_cast<const float4*>(ws + OFF_V2);
  float acc = 0.f;
#pragma unroll
  for (int k = 0; k < 10; ++k) {
    int j = g + 8 * k;
    if (j < 75) {
      float4 x = slab[row * 77 + j];
      float4 v = v4[j];
      acc = fmaf(x.x, v.x, fmaf(x.y, v.y, fmaf(x.z, v.z, fmaf(x.w, v.w, acc))));
    }
  }
  acc += __shfl_xor(acc, 1, 64);
  acc += __shfl_xor(acc, 2, 64);
  acc += __shfl_xor(acc, 4, 64);
  if (g == 0) ws[OFF_RAW + (size_t)sb * S2_ROWS + row] = acc;
}

// grid (40, 8) x 256: per-block softmax from RAW (redundant x8 per br; RAW is
// L2-resident 640KB) into sAtt, then h_prime GEMM + ELU. R18-measured branch.
__global__ __launch_bounds__(256) void k_hprime(const float* __restrict__ ws,
                                                float* __restrict__ out) {
  int br = blockIdx.x;
  int b = br / R, r = br % R;
  int t = threadIdx.x;
  __shared__ __align__(16) float sAtt[64 * 64];
  const float* raw = ws + OFF_RAW;
  for (int ne = t; ne < NE; ne += 256) {
    int n = ne >> 6;
    float v[R];
    float m = -1e30f;
#pragma unroll
    for (int rr = 0; rr < R; ++rr) {
      int brr = b * R + rr;
      float sc = raw[(size_t)brr * NE + ne] + ws[OFF_QA2 + brr] + ws[OFF_S1 + brr * N + n];
      sc = sc > 0.f ? sc : SLOPE * sc;
      v[rr] = sc;
      m = fmaxf(m, sc);
    }
    float s = 0.f;
#pragma unroll
    for (int rr = 0; rr < R; ++rr) { v[rr] = __expf(v[rr] - m); s += v[rr]; }
    sAtt[ne] = v[r] / s;
  }
  __syncthreads();
  int h = blockIdx.y * 64 + (t & 63);
  int ig = t >> 6;   // 0..3 -> rows ig*16..ig*16+15
  float acc[16] = {};
  const float* wo = ws + OFF_WO + (size_t)br * N * H;
  const float4* sAttf = reinterpret_cast<const float4*>(sAtt);
#pragma unroll 2
  for (int j4 = 0; j4 < 16; ++j4) {
    float w0 = wo[(size_t)(4 * j4 + 0) * H + h];
    float w1 = wo[(size_t)(4 * j4 + 1) * H + h];
    float w2 = wo[(size_t)(4 * j4 + 2) * H + h];
    float w3 = wo[(size_t)(4 * j4 + 3) * H + h];
#pragma unroll
    for (int ii = 0; ii < 16; ++ii) {
      float4 a4 = sAttf[(ig * 16 + ii) * 16 + j4];
      acc[ii] = fmaf(a4.x, w0, fmaf(a4.y, w1, fmaf(a4.z, w2, fmaf(a4.w, w3, acc[ii]))));
    }
  }
#pragma unroll
  for (int ii = 0; ii < 16; ++ii) {
    int i = ig * 16 + ii;
    float x = acc[ii];
    out[((size_t)br * N + i) * H + h] = x > 0.f ? x : expm1f(x);
  }
}

extern "C" void kernel_launch(void* const* d_in, const int* in_sizes, int n_in,
                              void* d_out, int out_size, void* d_ws, size_t ws_size,
                              hipStream_t stream) {
  const float* adj  = (const float*)d_in[0];
  const float* orig = (const float*)d_in[1];
  const float* ques = (const float*)d_in[2];
  const float* W    = (const float*)d_in[3];
  const float* a    = (const float*)d_in[4];
  float* out = (float*)d_out;
  float* ws  = (float*)d_ws;

  k_vecs<<<dim3(D + H), dim3(64), 0, stream>>>(W, a, ws);
  k_qproj_s1<<<dim3(BR), dim3(512), 0, stream>>>(ques, W, orig, ws);
  k_s2wo<<<dim3(WO_BLOCKS + S2_BLOCKS), dim3(256), 0, stream>>>(adj, orig, W, ws);
  k_hprime<<<dim3(BR, 8), dim3(256), 0, stream>>>(ws, out);
}

// Round 22
// 106.563 us; speedup vs baseline: 1.0927x; 1.0927x over previous
//
#include <hip/hip_runtime.h>
#include <math.h>

namespace {
constexpr int B = 4, R = 10, N = 64, E = 64, D = 300, H = 512;
constexpr int BR = B * R;        // 40
constexpr int NE = N * E;        // 4096
constexpr int S = BR * NE;       // 163840
constexpr float SLOPE = 0.2f;
constexpr int WO_BLOCKS = BR * 8;         // 320
constexpr int ATTN_BLOCKS = 512;          // 2048 waves
constexpr int ATTN_WAVES = ATTN_BLOCKS * 4;   // 2048
constexpr int UPW = (B * NE) / ATTN_WAVES;    // 8 units per wave

// ws layout (floats)
constexpr int OFF_V1  = 0;                 // 300   Wn @ a1
constexpr int OFF_V2  = OFF_V1 + 300;      // 300   Wn @ a2
constexpr int OFF_U1  = OFF_V2 + 300;      // 512   Wq @ a1
constexpr int OFF_U2  = OFF_U1 + H;        // 512   Wq @ a2
constexpr int OFF_QP  = OFF_U2 + H;        // 40*512 q_proj
constexpr int OFF_QA1 = OFF_QP + BR * H;   // 40
constexpr int OFF_QA2 = OFF_QA1 + BR;      // 40
constexpr int OFF_S1  = OFF_QA2 + BR;      // 2560  scores1[b,r,n] (incl. qa1)
constexpr int OFF_SC  = OFF_S1 + BR * N;   // 163840 attn (post-softmax)
constexpr int OFF_WO  = OFF_SC + S;        // 1310720 w_original
}

__device__ inline float waveReduce(float v) {
#pragma unroll
  for (int o = 32; o > 0; o >>= 1) v += __shfl_xor(v, o, 64);
  return v;
}

__device__ inline float dot4(float4 a, float4 b) {
  return a.x * b.x + a.y * b.y + a.z * b.z + a.w * b.w;
}

// grid 812 x 64: one wave per W row; dot with a1 and a2.
__global__ __launch_bounds__(64) void k_vecs(const float* __restrict__ W,
                                             const float* __restrict__ a,
                                             float* __restrict__ ws) {
  int row = blockIdx.x;
  int lane = threadIdx.x;
  const float4* rf  = reinterpret_cast<const float4*>(W + (size_t)row * H);
  const float4* a1f = reinterpret_cast<const float4*>(a);
  const float4* a2f = reinterpret_cast<const float4*>(a + H);
  float4 x0 = rf[lane], x1 = rf[64 + lane];
  float4 p0 = a1f[lane], p1 = a1f[64 + lane];
  float4 q0 = a2f[lane], q1 = a2f[64 + lane];
  float s1 = dot4(x0, p0) + dot4(x1, p1);
  float s2 = dot4(x0, q0) + dot4(x1, q1);
  s1 = waveReduce(s1);
  s2 = waveReduce(s2);
  if (lane == 0) {
    if (row < D) { ws[OFF_V1 + row] = s1; ws[OFF_V2 + row] = s2; }
    else         { ws[OFF_U1 + (row - D)] = s1; ws[OFF_U2 + (row - D)] = s2; }
  }
}

// grid 40 x 512: q_proj (4-way ILP accumulators) + qa1/qa2 + scores1 (2-row batch).
__global__ __launch_bounds__(512) void k_qproj_s1(const float* __restrict__ ques,
                                                  const float* __restrict__ W,
                                                  const float* __restrict__ orig,
                                                  float* __restrict__ ws) {
  int br = blockIdx.x, h = threadIdx.x;
  __shared__ float qs[H];
  __shared__ float red[16];
  __shared__ float qa1s;
  qs[h] = ques[(size_t)br * H + h];
  __syncthreads();
  float ac0 = 0.f, ac1 = 0.f, ac2 = 0.f, ac3 = 0.f;
#pragma unroll 4
  for (int q = 0; q < H; q += 4) {
    ac0 = fmaf(qs[q + 0], W[(size_t)(D + q + 0) * H + h], ac0);
    ac1 = fmaf(qs[q + 1], W[(size_t)(D + q + 1) * H + h], ac1);
    ac2 = fmaf(qs[q + 2], W[(size_t)(D + q + 2) * H + h], ac2);
    ac3 = fmaf(qs[q + 3], W[(size_t)(D + q + 3) * H + h], ac3);
  }
  float acc = (ac0 + ac1) + (ac2 + ac3);
  ws[OFF_QP + br * H + h] = acc;
  float p1 = qs[h] * ws[OFF_U1 + h];
  float p2 = qs[h] * ws[OFF_U2 + h];
  p1 = waveReduce(p1);
  p2 = waveReduce(p2);
  int lane = h & 63, wave = h >> 6;
  if (lane == 0) { red[wave] = p1; red[8 + wave] = p2; }
  __syncthreads();
  if (h == 0) {
    float t1 = 0.f, t2 = 0.f;
#pragma unroll
    for (int i = 0; i < 8; ++i) { t1 += red[i]; t2 += red[8 + i]; }
    ws[OFF_QA1 + br] = t1;
    ws[OFF_QA2 + br] = t2;
    qa1s = t1;
  }
  __syncthreads();
  float qa1 = qa1s;
  const float4* vf = reinterpret_cast<const float4*>(ws + OFF_V1);
  float4 va = vf[lane];
  float4 vb = (lane < 11) ? vf[64 + lane] : make_float4(0.f, 0.f, 0.f, 0.f);
  for (int n2 = wave * 8; n2 < wave * 8 + 8; n2 += 2) {
    const float4* rf0 = reinterpret_cast<const float4*>(orig + ((size_t)br * N + n2) * D);
    const float4* rf1 = reinterpret_cast<const float4*>(orig + ((size_t)br * N + n2 + 1) * D);
    float a0 = dot4(rf0[lane], va);
    float a1 = dot4(rf1[lane], va);
    if (lane < 11) {
      a0 += dot4(rf0[64 + lane], vb);
      a1 += dot4(rf1[64 + lane], vb);
    }
#pragma unroll
    for (int o = 32; o > 0; o >>= 1) {
      a0 += __shfl_xor(a0, o, 64);
      a1 += __shfl_xor(a1, o, 64);
    }
    if (lane == 0) {
      ws[OFF_S1 + br * N + n2]     = a0 + qa1;
      ws[OFF_S1 + br * N + n2 + 1] = a1 + qa1;
    }
  }
}

__device__ __forceinline__ void attn_load_x(const float* __restrict__ adj, int u,
                                            int lane, float4 (&x)[R]) {
  const float* base = adj + ((size_t)(u >> 12) * R * NE + (u & 4095)) * D;
#pragma unroll
  for (int r = 0; r < R; ++r)
    x[r] = reinterpret_cast<const float4*>(base + (size_t)r * NE * D)[lane];
}

__device__ __forceinline__ void attn_compute(const float* __restrict__ adj,
                                             float* __restrict__ ws, int u, int lane,
                                             const float4 (&x)[R],
                                             float4 va, float4 vb) {
  int b = u >> 12, ne = u & 4095, n = ne >> 6, brb = b * R;
  const float* base = adj + ((size_t)b * R * NE + ne) * D;
  bool tl = lane < 11;
  float4 y[R];
  if (tl) {
#pragma unroll
    for (int r = 0; r < R; ++r)
      y[r] = reinterpret_cast<const float4*>(base + (size_t)r * NE * D)[64 + lane];
  }
  float add[R];
#pragma unroll
  for (int r = 0; r < R; ++r)
    add[r] = ws[OFF_QA2 + brb + r] + ws[OFF_S1 + (brb + r) * N + n];
  float acc[R];
#pragma unroll
  for (int r = 0; r < R; ++r) acc[r] = dot4(x[r], va);
  if (tl) {
#pragma unroll
    for (int r = 0; r < R; ++r) acc[r] += dot4(y[r], vb);
  }
#pragma unroll
  for (int o = 32; o > 0; o >>= 1) {
#pragma unroll
    for (int r = 0; r < R; ++r) acc[r] += __shfl_xor(acc[r], o, 64);
  }
  float m = -1e30f;
#pragma unroll
  for (int r = 0; r < R; ++r) {
    float sc = acc[r] + add[r];
    sc = sc > 0.f ? sc : SLOPE * sc;
    acc[r] = sc;
    m = fmaxf(m, sc);
  }
  float s = 0.f;
#pragma unroll
  for (int r = 0; r < R; ++r) { acc[r] = __expf(acc[r] - m); s += acc[r]; }
  float inv = 1.f / s;
  if (lane == 0) {
#pragma unroll
    for (int r = 0; r < R; ++r)
      ws[OFF_SC + (size_t)(brb + r) * NE + ne] = acc[r] * inv;
  }
}

// grid 832 x 256, block-split (R17 structure, deepened pipeline):
//   blocks 0..319:  wo GEMM (br, h0), BK=30 -> 15360B LDS (R18-verified) so
//                   the shared static LDS no longer caps attn residency.
//   blocks 320..831: persistent attn, UPW=8, DEPTH-2 x-prefetch via 3 static
//                   register buffers (hand-unrolled schedule): unit i+2's 10
//                   row-loads are issued before unit i's compute -> ~2x the
//                   latency coverage of R17's depth-1.
__global__ __launch_bounds__(256) void k_attn_wo(const float* __restrict__ adj,
                                                 const float* __restrict__ orig,
                                                 const float* __restrict__ W,
                                                 float* __restrict__ ws) {
  __shared__ __align__(16) float smem[64 * 30 + 30 * 64];   // 15360 B
  int t = threadIdx.x;
  if (blockIdx.x < WO_BLOCKS) {
    // ---- w_original tile GEMM, BK=30 (R18 branch, verbatim) ----
    int bi = blockIdx.x;
    int br = bi >> 3, h0 = (bi & 7) * 64;
    float* sA = smem;             // 64 x 30
    float* sB = smem + 1920;      // 30 x 64
    const float4* sBf = reinterpret_cast<const float4*>(sB);
    int tn = t >> 4, th = t & 15;
    float acc[4][4] = {};
    for (int k0 = 0; k0 < D; k0 += 30) {
      __syncthreads();
      for (int idx = t; idx < 64 * 30; idx += 256) {
        int n = idx / 30, kk = idx % 30;
        sA[idx] = orig[((size_t)br * N + n) * D + k0 + kk];
      }
      for (int idx = t; idx < 30 * 64; idx += 256) {
        int kk = idx >> 6, hh = idx & 63;
        sB[idx] = W[(size_t)(k0 + kk) * H + h0 + hh];
      }
      __syncthreads();
#pragma unroll 5
      for (int kk = 0; kk < 30; ++kk) {
        float av[4];
#pragma unroll
        for (int i = 0; i < 4; ++i) av[i] = sA[(tn * 4 + i) * 30 + kk];
        float4 bv = sBf[kk * 16 + th];
#pragma unroll
        for (int i = 0; i < 4; ++i) {
          acc[i][0] = fmaf(av[i], bv.x, acc[i][0]);
          acc[i][1] = fmaf(av[i], bv.y, acc[i][1]);
          acc[i][2] = fmaf(av[i], bv.z, acc[i][2]);
          acc[i][3] = fmaf(av[i], bv.w, acc[i][3]);
        }
      }
    }
#pragma unroll
    for (int i = 0; i < 4; ++i) {
      int n = tn * 4 + i;
#pragma unroll
      for (int j = 0; j < 4; ++j) {
        int h = h0 + th * 4 + j;
        ws[OFF_WO + ((size_t)br * N + n) * H + h] = acc[i][j] + ws[OFF_QP + br * H + h];
      }
    }
    return;
  }
  // ---- persistent attn, depth-2 prefetch, hand-unrolled static schedule ----
  int aw = (blockIdx.x - WO_BLOCKS) * 4 + (t >> 6);   // 0..2047
  int lane = t & 63;
  const float4* vf = reinterpret_cast<const float4*>(ws + OFF_V2);
  float4 va = vf[lane];
  float4 vb = (lane < 11) ? vf[64 + lane] : make_float4(0.f, 0.f, 0.f, 0.f);
  float4 x0[R], x1[R], x2[R];
  attn_load_x(adj, aw + 0 * ATTN_WAVES, lane, x0);
  attn_load_x(adj, aw + 1 * ATTN_WAVES, lane, x1);
  // i=0..7: compute buf[i%3] (unit i), prefetch buf[(i+2)%3] <- unit i+2.
  attn_load_x(adj, aw + 2 * ATTN_WAVES, lane, x2);
  attn_compute(adj, ws, aw + 0 * ATTN_WAVES, lane, x0, va, vb);
  attn_load_x(adj, aw + 3 * ATTN_WAVES, lane, x0);
  attn_compute(adj, ws, aw + 1 * ATTN_WAVES, lane, x1, va, vb);
  attn_load_x(adj, aw + 4 * ATTN_WAVES, lane, x1);
  attn_compute(adj, ws, aw + 2 * ATTN_WAVES, lane, x2, va, vb);
  attn_load_x(adj, aw + 5 * ATTN_WAVES, lane, x2);
  attn_compute(adj, ws, aw + 3 * ATTN_WAVES, lane, x0, va, vb);
  attn_load_x(adj, aw + 6 * ATTN_WAVES, lane, x0);
  attn_compute(adj, ws, aw + 4 * ATTN_WAVES, lane, x1, va, vb);
  attn_load_x(adj, aw + 7 * ATTN_WAVES, lane, x1);
  attn_compute(adj, ws, aw + 5 * ATTN_WAVES, lane, x2, va, vb);
  attn_compute(adj, ws, aw + 6 * ATTN_WAVES, lane, x0, va, vb);
  attn_compute(adj, ws, aw + 7 * ATTN_WAVES, lane, x1, va, vb);
}

// grid (40, 8) x 256: h_prime[br] = attn[br] @ w_original[br], then ELU.
__global__ __launch_bounds__(256) void k_hprime(const float* __restrict__ ws,
                                                float* __restrict__ out) {
  int br = blockIdx.x;
  int h = blockIdx.y * 64 + (threadIdx.x & 63);
  int ig = threadIdx.x >> 6;   // 0..3 -> rows ig*16..ig*16+15
  __shared__ __align__(16) float sAtt[64 * 64];
  const float* att = ws + OFF_SC + (size_t)br * NE;
  for (int idx = threadIdx.x; idx < 4096; idx += 256) sAtt[idx] = att[idx];
  __syncthreads();
  float acc[16] = {};
  const float* wo = ws + OFF_WO + (size_t)br * N * H;
  const float4* sAttf = reinterpret_cast<const float4*>(sAtt);
#pragma unroll 2
  for (int j4 = 0; j4 < 16; ++j4) {
    float w0 = wo[(size_t)(4 * j4 + 0) * H + h];
    float w1 = wo[(size_t)(4 * j4 + 1) * H + h];
    float w2 = wo[(size_t)(4 * j4 + 2) * H + h];
    float w3 = wo[(size_t)(4 * j4 + 3) * H + h];
#pragma unroll
    for (int ii = 0; ii < 16; ++ii) {
      float4 a4 = sAttf[(ig * 16 + ii) * 16 + j4];
      acc[ii] = fmaf(a4.x, w0, fmaf(a4.y, w1, fmaf(a4.z, w2, fmaf(a4.w, w3, acc[ii]))));
    }
  }
#pragma unroll
  for (int ii = 0; ii < 16; ++ii) {
    int i = ig * 16 + ii;
    float x = acc[ii];
    out[((size_t)br * N + i) * H + h] = x > 0.f ? x : expm1f(x);
  }
}

extern "C" void kernel_launch(void* const* d_in, const int* in_sizes, int n_in,
                              void* d_out, int out_size, void* d_ws, size_t ws_size,
                              hipStream_t stream) {
  const float* adj  = (const float*)d_in[0];
  const float* orig = (const float*)d_in[1];
  const float* ques = (const float*)d_in[2];
  const float* W    = (const float*)d_in[3];
  const float* a    = (const float*)d_in[4];
  float* out = (float*)d_out;
  float* ws  = (float*)d_ws;

  k_vecs<<<dim3(D + H), dim3(64), 0, stream>>>(W, a, ws);
  k_qproj_s1<<<dim3(BR), dim3(512), 0, stream>>>(ques, W, orig, ws);
  k_attn_wo<<<dim3(WO_BLOCKS + ATTN_BLOCKS), dim3(256), 0, stream>>>(adj, orig, W, ws);
  k_hprime<<<dim3(BR, 8), dim3(256), 0, stream>>>(ws, out);
}